// Round 11
// baseline (1781.156 us; speedup 1.0000x reference)
//
#include <hip/hip_runtime.h>
#include <stdint.h>

#define B_    1024
#define TX_   512
#define TY_   32
#define NA_   64
#define NS_   128
#define VIN_  64
#define VOUT_ 32

typedef short v8s __attribute__((ext_vector_type(8)));   // 8 bf16 (4 VGPRs)
typedef float v4f __attribute__((ext_vector_type(4)));   // 4 fp32 acc

__device__ __forceinline__ unsigned short f2bf(float f) {
  union { float f; uint32_t u; } v; v.f = f;
  return (unsigned short)((v.u + 0x7fffu + ((v.u >> 16) & 1u)) >> 16);  // RNE
}
__device__ __forceinline__ float bflo(uint32_t p) { union { uint32_t u; float f; } v; v.u = p << 16; return v.f; }
__device__ __forceinline__ float bfhi(uint32_t p) { union { uint32_t u; float f; } v; v.u = p & 0xffff0000u; return v.f; }
__device__ __forceinline__ float sigm(float x)   { return 1.0f / (1.0f + __expf(-x)); }
__device__ __forceinline__ float tanh_f(float x) { return 1.0f - 2.0f / (__expf(2.0f * x) + 1.0f); }

// ---------------- prep: Wcat = [Wih_p | Whh_p] -> bf16 in MFMA B-frag order.
// frag f covers rows [(f>>3)*16, +16) x cols [(f&7)*32, +32).
// lane (n = lane&15, q = lane>>4) element j holds Wcat[(f>>3)*16 + n][(f&7)*32 + q*8 + j].
// linear short index = f*512 + lane*8 + j  -> 16B/lane coalesced v8s loads in k_dec.
// k_dec (512 thr): frag f = (wv*4+nt)*8+kt -> rows 64wv+16nt, cols kt*32.
__global__ __launch_bounds__(256) void k_prep(const float* __restrict__ Wih_p,
                                              const float* __restrict__ Whh_p,
                                              unsigned short* __restrict__ Wsw) {
  int i = blockIdx.x * 256 + threadIdx.x;   // < 131072
  int j = i & 7, lane = (i >> 3) & 63, f = i >> 9;
  int r = (f >> 3) * 16 + (lane & 15);
  int c = (f & 7) * 32 + (lane >> 4) * 8 + j;
  float w = (c < 128) ? Wih_p[r * 128 + c] : Whh_p[r * 128 + (c - 128)];
  Wsw[i] = f2bf(w);
}

// ---------------- encoder: 64 blocks x 512 thr = (64 batch-groups, fwd+bwd MERGED).
// R11: waves 0-3 = fwd hidden slices, waves 4-7 = bwd (dir = wv8>>2). Two independent
// recurrences per SIMD (2 waves/SIMD) hide each other's MFMA/LDS/barrier latency —
// k_enc was 1 wave/SIMD (zero hiding) and ~600us of the 1417us total.
// Double-buffered hl: write hl[t^1], read hl[t] -> ONE barrier per step (end-of-step
// barrier covers write(t)->read(t+1) and read(t)->write(t+1) both).
__global__ __launch_bounds__(512) void k_enc(
    const float* __restrict__ X,
    const float* __restrict__ Wih_f, const float* __restrict__ Whh_f,
    const float* __restrict__ bih_f, const float* __restrict__ bhh_f,
    const float* __restrict__ Wih_b, const float* __restrict__ Whh_b,
    const float* __restrict__ bih_b, const float* __restrict__ bhh_b,
    unsigned short* __restrict__ pre16)
{
  const int tid = threadIdx.x, lane = tid & 63, wv8 = tid >> 6;
  const int dir = wv8 >> 2, wv = wv8 & 3;
  const int b0 = blockIdx.x * 16;
  const int n = lane & 15, q = lane >> 4, hs = wv * 16;
  const float* Wih = dir ? Wih_b : Wih_f;
  const float* Whh = dir ? Whh_b : Whh_f;
  const float* bih = dir ? bih_b : bih_f;
  const float* bhh = dir ? bhh_b : bhh_f;

  __shared__ __align__(16) unsigned short hl[2][2][16 * 72];  // [dbuf][dir], 144B rows

  v8s wx[4][2], wh[4][2];
  float bias[4];
#pragma unroll
  for (int g = 0; g < 4; ++g) {
    int row = g * 64 + hs + n;
    bias[g] = bih[row] + bhh[row];
#pragma unroll
    for (int kt = 0; kt < 2; ++kt) {
      const float* pi = Wih + row * 64 + kt * 32 + q * 8;
      const float* ph = Whh + row * 64 + kt * 32 + q * 8;
      v8s a, bb;
#pragma unroll
      for (int j = 0; j < 8; ++j) { a[j] = (short)f2bf(pi[j]); bb[j] = (short)f2bf(ph[j]); }
      wx[g][kt] = a; wh[g][kt] = bb;
    }
  }
  for (int i = tid; i < 2 * 16 * 36; i += 512) ((uint32_t*)hl[0])[i] = 0u;  // zero hl[0][0..1]

  float c[4] = {0.f, 0.f, 0.f, 0.f};
  const float* xrow = X + (size_t)(b0 + n) * (TX_ * VIN_) + q * 8;  // A-frag m = lane&15
  int t0 = dir ? (TX_ - 1) : 0;
  float4 pf0 = *(const float4*)(xrow + t0 * VIN_ + 0);
  float4 pf1 = *(const float4*)(xrow + t0 * VIN_ + 4);
  float4 pf2 = *(const float4*)(xrow + t0 * VIN_ + 32);
  float4 pf3 = *(const float4*)(xrow + t0 * VIN_ + 36);
  __syncthreads();

  for (int t = 0; t < TX_; ++t) {
    v8s xa0, xa1;
    xa0[0]=(short)f2bf(pf0.x); xa0[1]=(short)f2bf(pf0.y); xa0[2]=(short)f2bf(pf0.z); xa0[3]=(short)f2bf(pf0.w);
    xa0[4]=(short)f2bf(pf1.x); xa0[5]=(short)f2bf(pf1.y); xa0[6]=(short)f2bf(pf1.z); xa0[7]=(short)f2bf(pf1.w);
    xa1[0]=(short)f2bf(pf2.x); xa1[1]=(short)f2bf(pf2.y); xa1[2]=(short)f2bf(pf2.z); xa1[3]=(short)f2bf(pf2.w);
    xa1[4]=(short)f2bf(pf3.x); xa1[5]=(short)f2bf(pf3.y); xa1[6]=(short)f2bf(pf3.z); xa1[7]=(short)f2bf(pf3.w);
    int tn = (t + 1 < TX_) ? t + 1 : t;
    int ti = dir ? (TX_ - 1 - tn) : tn;
    pf0 = *(const float4*)(xrow + ti * VIN_ + 0);
    pf1 = *(const float4*)(xrow + ti * VIN_ + 4);
    pf2 = *(const float4*)(xrow + ti * VIN_ + 32);
    pf3 = *(const float4*)(xrow + ti * VIN_ + 36);

    const char* hb_ = (const char*)hl[t & 1][dir];
    v8s ha0 = *(const v8s*)(hb_ + (lane & 15) * 144 + q * 16);
    v8s ha1 = *(const v8s*)(hb_ + (lane & 15) * 144 + 64 + q * 16);
    v4f acc[4];
#pragma unroll
    for (int g = 0; g < 4; ++g) {
      v4f a = {bias[g], bias[g], bias[g], bias[g]};
      a = __builtin_amdgcn_mfma_f32_16x16x32_bf16(xa0, wx[g][0], a, 0, 0, 0);
      a = __builtin_amdgcn_mfma_f32_16x16x32_bf16(xa1, wx[g][1], a, 0, 0, 0);
      a = __builtin_amdgcn_mfma_f32_16x16x32_bf16(ha0, wh[g][0], a, 0, 0, 0);
      a = __builtin_amdgcn_mfma_f32_16x16x32_bf16(ha1, wh[g][1], a, 0, 0, 0);
      acc[g] = a;
    }
    int t_out = dir ? (TX_ - 1 - t) : t;
    char* hw_ = (char*)hl[(t & 1) ^ 1][dir];
#pragma unroll
    for (int r = 0; r < 4; ++r) {   // C/D: col=lane&15 (hidden), row=q*4+r (batch)
      float cc = sigm(acc[1][r]) * c[r] + sigm(acc[0][r]) * tanh_f(acc[2][r]);
      c[r] = cc;
      float h = sigm(acc[3][r]) * tanh_f(cc);
      int m = q * 4 + r;
      unsigned short hb = f2bf(h);
      *((unsigned short*)(hw_ + m * 144) + hs + n) = hb;
      pre16[((size_t)(b0 + m) * TX_ + t_out) * NS_ + dir * 64 + hs + n] = hb;
    }
    __syncthreads();   // write(t)->read(t+1) on hl[t^1]; read(t)->write(t+1) on hl[t]
  }
}

// ---------------- decoder: 1 block per batch element, 512 threads (8 waves, 2 waves/SIMD).
// Locked-in: VGPR cap = 65536/block (R1-R5); po LDS-resident (R8); 1 block/CU.
// Structure: R9 weight-stream + R10 6-barrier step (best measured: 718us).
#define PO_   0
#define PP_   139264
#define EA_   149504
#define RED_  151552
#define ZB_   155648
#define SL_   157696
#define XPK_  158208
#define QV_   159232
#define RR_   159296
#define DSM_  159360

__global__ __launch_bounds__(512) void k_dec(
    const unsigned short* __restrict__ pre16,
    const unsigned short* __restrict__ Wsw,
    const float* __restrict__ W1, const float* __restrict__ b1,
    const float* __restrict__ W2, const float* __restrict__ b2,
    const float* __restrict__ W3, const float* __restrict__ b3,
    const float* __restrict__ bih_p, const float* __restrict__ bhh_p,
    float* __restrict__ Lg)
{
  extern __shared__ char smem[];
  char* po = smem + PO_;
  unsigned short* P = (unsigned short*)(smem + PP_);
  float* ea  = (float*)(smem + EA_);
  float* red = (float*)(smem + RED_);
  float* zbf = (float*)(smem + ZB_);
  float* sl  = (float*)(smem + SL_);
  uint32_t* xpk = (uint32_t*)(smem + XPK_);
  float* qv  = (float*)(smem + QV_);
  float* rr  = (float*)(smem + RR_);

  const int b = blockIdx.x, tid = threadIdx.x, lane = tid & 63, wv = tid >> 6;

  { // stage pre_out[b] -> padded LDS rows (272B stride, b128-aligned)
    const uint4* src = (const uint4*)((const char*)pre16 + (size_t)b * (TX_ * NS_ * 2));
    for (int i = tid; i < TX_ * 16; i += 512) {
      int t = i >> 4, d8 = i & 15;
      *(uint4*)(po + t * 272 + d8 * 16) = src[i];
    }
  }
  if (tid < 128) { sl[tid] = 0.f; xpk[tid] = 0u; }
  if (tid < 16) qv[tid] = 0.f;               // q for step 0: s0 = 0 -> q = 0
  float* w1p = (float*)(smem + RED_);   // 1280-float staging (RED_+ZB_ space, prologue only)
  for (int i = tid; i < 1280; i += 512) { int g = i >> 7, k = i & 127; w1p[i] = W1[g * 256 + 128 + k]; }
  __syncthreads();
  { // P[t][g] = pre_out[t] @ W1[:,128:].T + b1   (thread = t)
    int t = tid;
    float a[10];
#pragma unroll
    for (int g = 0; g < 10; ++g) a[g] = b1[g];
    for (int k2 = 0; k2 < 64; ++k2) {
      uint32_t pr = *(const uint32_t*)(po + t * 272 + k2 * 4);
      float lo = bflo(pr), hi = bfhi(pr);
#pragma unroll
      for (int g = 0; g < 10; ++g) a[g] += lo * w1p[g * 128 + 2 * k2] + hi * w1p[g * 128 + 2 * k2 + 1];
    }
#pragma unroll
    for (int g = 0; g < 10; ++g) P[t * 10 + g] = f2bf(a[g]);
  }

  // per-wave weight stream base: frag j = nt*8+kt at wp[j*64]; wave wv owns z rows [64wv, 64wv+64)
  const v8s* wp = (const v8s*)Wsw + (size_t)(wv * 32) * 64 + lane;
  float bp4[4];
#pragma unroll
  for (int nt = 0; nt < 4; ++nt) {
    int r = wv * 64 + nt * 16 + (lane & 15);
    bp4[nt] = bih_p[r] + bhh_p[r];
  }
  float creg = 0.f;
  __syncthreads();

  for (int ty = 0; ty < TY_; ++ty) {
    // ---- step-top weight issue: nt0+nt1 (16 frags, 64 VGPRs); covered by e-phase+context.
    v8s wA[4], wB[4], wC[4], wD[4], wE[4];
#pragma unroll
    for (int k = 0; k < 4; ++k) wA[k] = wp[k * 64];
#pragma unroll
    for (int k = 0; k < 4; ++k) wB[k] = wp[(4 + k) * 64];
#pragma unroll
    for (int k = 0; k < 4; ++k) wC[k] = wp[(8 + k) * 64];
#pragma unroll
    for (int k = 0; k < 4; ++k) wD[k] = wp[(12 + k) * 64];

    // ---- e_t (thread = t); no max-subtraction (e = relu(.) bounded ~1, exp <= ~3).
    // Single barrier: ea[t] = p UNNORMALIZED; /S deferred to the fold phase.
    {
      float qr[10];
#pragma unroll
      for (int g = 0; g < 10; ++g) qr[g] = qv[g];
      const uint32_t* Pt = (const uint32_t*)(const void*)P + tid * 5;
      float acc = b2[0];
#pragma unroll
      for (int i = 0; i < 5; ++i) {
        uint32_t pr = Pt[i];
        acc += W2[2 * i]     * tanh_f(bflo(pr) + qr[2 * i]);
        acc += W2[2 * i + 1] * tanh_f(bfhi(pr) + qr[2 * i + 1]);
      }
      float e = fmaxf(acc, 0.f);
      float p = __expf(e);
      ea[tid] = p;
      float s = p;
#pragma unroll
      for (int off = 1; off < 64; off <<= 1) s += __shfl_xor(s, off);
      if (lane == 0) rr[wv] = s;
    }
    __syncthreads();
    // ---- context partials = sum_t p_t * pre_out[t]  (lane=(d8,g4), t = i*32 + wv*4 + g4)
    {
      int d8 = lane & 15, g4 = lane >> 4, tg = wv * 4 + g4;
      float p8[8];
#pragma unroll
      for (int j = 0; j < 8; ++j) p8[j] = 0.f;
      for (int i = 0; i < 16; ++i) {
        int t = i * 32 + tg;
        float al = ea[t];
        uint4 pk = *(const uint4*)(po + t * 272 + d8 * 16);
        p8[0] += al * bflo(pk.x); p8[1] += al * bfhi(pk.x);
        p8[2] += al * bflo(pk.y); p8[3] += al * bfhi(pk.y);
        p8[4] += al * bflo(pk.z); p8[5] += al * bfhi(pk.z);
        p8[6] += al * bflo(pk.w); p8[7] += al * bfhi(pk.w);
      }
#pragma unroll
      for (int off = 16; off < 64; off <<= 1) {
#pragma unroll
        for (int j = 0; j < 8; ++j) p8[j] += __shfl_xor(p8[j], off);
      }
      if (lane < 16) {
        float4* dst = (float4*)&red[wv * 128 + d8 * 8];
        dst[0] = make_float4(p8[0], p8[1], p8[2], p8[3]);
        dst[1] = make_float4(p8[4], p8[5], p8[6], p8[7]);
      }
    }
    // ---- post-context weight issue: nt2-lo (wE). p8 dead here; live bufs = 5 (80 VGPR).
#pragma unroll
    for (int k = 0; k < 4; ++k) wE[k] = wp[(16 + k) * 64];
    __syncthreads();
    // ---- fold 8 wave-partials, normalize by S (from rr), pack ctx -> xpk[0..63]
    if (tid < 64) {
      float s8 = rr[tid & 7];
#pragma unroll
      for (int off = 1; off < 8; off <<= 1) s8 += __shfl_xor(s8, off);
      float rS = 1.0f / s8;
      float v0 = 0.f, v1 = 0.f;
#pragma unroll
      for (int w = 0; w < 8; ++w) { v0 += red[w * 128 + 2 * tid]; v1 += red[w * 128 + 2 * tid + 1]; }
      xpk[tid] = ((uint32_t)f2bf(v1 * rS) << 16) | (uint32_t)f2bf(v0 * rS);
    }
    __syncthreads();
    // ---- z = Wcat @ [ctx; s] + bp via MFMA. Broadcast-A: all 16 A-rows hold x (row 0 of
    // D is unaffected), so every lane loads xpk directly (LDS broadcast) - no cndmask.
    // Dual-acc interleave breaks the 8-deep dependent MFMA chains. Refills reuse dead bufs.
    {
      const char* xb = (const char*)xpk + (lane >> 4) * 16;
      v4f a0 = {0.f, 0.f, 0.f, 0.f}, a1 = {0.f, 0.f, 0.f, 0.f};
      v8s x0, x1;
      x0 = *(const v8s*)(xb + 0 * 64);
      x1 = *(const v8s*)(xb + 1 * 64);
      a0 = __builtin_amdgcn_mfma_f32_16x16x32_bf16(x0, wA[0], a0, 0, 0, 0);
      a1 = __builtin_amdgcn_mfma_f32_16x16x32_bf16(x0, wC[0], a1, 0, 0, 0);
      a0 = __builtin_amdgcn_mfma_f32_16x16x32_bf16(x1, wA[1], a0, 0, 0, 0);
      a1 = __builtin_amdgcn_mfma_f32_16x16x32_bf16(x1, wC[1], a1, 0, 0, 0);
      x0 = *(const v8s*)(xb + 2 * 64);
      x1 = *(const v8s*)(xb + 3 * 64);
      a0 = __builtin_amdgcn_mfma_f32_16x16x32_bf16(x0, wA[2], a0, 0, 0, 0);
      a1 = __builtin_amdgcn_mfma_f32_16x16x32_bf16(x0, wC[2], a1, 0, 0, 0);
      a0 = __builtin_amdgcn_mfma_f32_16x16x32_bf16(x1, wA[3], a0, 0, 0, 0);
      a1 = __builtin_amdgcn_mfma_f32_16x16x32_bf16(x1, wC[3], a1, 0, 0, 0);
      // wA,wC consumed -> stream nt2-hi into wA, nt3-lo into wC
#pragma unroll
      for (int k = 0; k < 4; ++k) wA[k] = wp[(20 + k) * 64];
#pragma unroll
      for (int k = 0; k < 4; ++k) wC[k] = wp[(24 + k) * 64];
      x0 = *(const v8s*)(xb + 4 * 64);
      x1 = *(const v8s*)(xb + 5 * 64);
      a0 = __builtin_amdgcn_mfma_f32_16x16x32_bf16(x0, wB[0], a0, 0, 0, 0);
      a1 = __builtin_amdgcn_mfma_f32_16x16x32_bf16(x0, wD[0], a1, 0, 0, 0);
      a0 = __builtin_amdgcn_mfma_f32_16x16x32_bf16(x1, wB[1], a0, 0, 0, 0);
      a1 = __builtin_amdgcn_mfma_f32_16x16x32_bf16(x1, wD[1], a1, 0, 0, 0);
      x0 = *(const v8s*)(xb + 6 * 64);
      x1 = *(const v8s*)(xb + 7 * 64);
      a0 = __builtin_amdgcn_mfma_f32_16x16x32_bf16(x0, wB[2], a0, 0, 0, 0);
      a1 = __builtin_amdgcn_mfma_f32_16x16x32_bf16(x0, wD[2], a1, 0, 0, 0);
      a0 = __builtin_amdgcn_mfma_f32_16x16x32_bf16(x1, wB[3], a0, 0, 0, 0);
      a1 = __builtin_amdgcn_mfma_f32_16x16x32_bf16(x1, wD[3], a1, 0, 0, 0);
      // wB,wD consumed -> stream nt3-hi into wB
#pragma unroll
      for (int k = 0; k < 4; ++k) wB[k] = wp[(28 + k) * 64];
      if (lane < 16) {
        zbf[wv * 64 + lane]      = a0[0] + bp4[0];   // D[0][n] on lanes 0..15, reg 0
        zbf[wv * 64 + 16 + lane] = a1[0] + bp4[1];
      }
      v4f a2 = {0.f, 0.f, 0.f, 0.f}, a3 = {0.f, 0.f, 0.f, 0.f};
      x0 = *(const v8s*)(xb + 0 * 64);
      x1 = *(const v8s*)(xb + 1 * 64);
      a2 = __builtin_amdgcn_mfma_f32_16x16x32_bf16(x0, wE[0], a2, 0, 0, 0);
      a3 = __builtin_amdgcn_mfma_f32_16x16x32_bf16(x0, wC[0], a3, 0, 0, 0);
      a2 = __builtin_amdgcn_mfma_f32_16x16x32_bf16(x1, wE[1], a2, 0, 0, 0);
      a3 = __builtin_amdgcn_mfma_f32_16x16x32_bf16(x1, wC[1], a3, 0, 0, 0);
      x0 = *(const v8s*)(xb + 2 * 64);
      x1 = *(const v8s*)(xb + 3 * 64);
      a2 = __builtin_amdgcn_mfma_f32_16x16x32_bf16(x0, wE[2], a2, 0, 0, 0);
      a3 = __builtin_amdgcn_mfma_f32_16x16x32_bf16(x0, wC[2], a3, 0, 0, 0);
      a2 = __builtin_amdgcn_mfma_f32_16x16x32_bf16(x1, wE[3], a2, 0, 0, 0);
      a3 = __builtin_amdgcn_mfma_f32_16x16x32_bf16(x1, wC[3], a3, 0, 0, 0);
      x0 = *(const v8s*)(xb + 4 * 64);
      x1 = *(const v8s*)(xb + 5 * 64);
      a2 = __builtin_amdgcn_mfma_f32_16x16x32_bf16(x0, wA[0], a2, 0, 0, 0);
      a3 = __builtin_amdgcn_mfma_f32_16x16x32_bf16(x0, wB[0], a3, 0, 0, 0);
      a2 = __builtin_amdgcn_mfma_f32_16x16x32_bf16(x1, wA[1], a2, 0, 0, 0);
      a3 = __builtin_amdgcn_mfma_f32_16x16x32_bf16(x1, wB[1], a3, 0, 0, 0);
      x0 = *(const v8s*)(xb + 6 * 64);
      x1 = *(const v8s*)(xb + 7 * 64);
      a2 = __builtin_amdgcn_mfma_f32_16x16x32_bf16(x0, wA[2], a2, 0, 0, 0);
      a3 = __builtin_amdgcn_mfma_f32_16x16x32_bf16(x0, wB[2], a3, 0, 0, 0);
      a2 = __builtin_amdgcn_mfma_f32_16x16x32_bf16(x1, wA[3], a2, 0, 0, 0);
      a3 = __builtin_amdgcn_mfma_f32_16x16x32_bf16(x1, wB[3], a3, 0, 0, 0);
      if (lane < 16) {
        zbf[wv * 64 + 32 + lane] = a2[0] + bp4[2];
        zbf[wv * 64 + 48 + lane] = a3[0] + bp4[3];
      }
    }
    __syncthreads();
    if (tid < 128) {   // gate merge, torch order i,f,g,o
      float zi = zbf[tid], zf = zbf[128 + tid], zg = zbf[256 + tid], zo = zbf[384 + tid];
      creg = sigm(zf) * creg + sigm(zi) * tanh_f(zg);
      sl[tid] = sigm(zo) * tanh_f(creg);
    }
    __syncthreads();
    // ---- merged phase: wave0 packs s; waves 1&6 split next-step q (5 gates each);
    //      waves 2-5 in-wave logits with DIRECT Lg store (v=(wv-2)*8+(lane>>3), kg=lane&7)
    if (wv == 0) {
      xpk[64 + lane] = ((uint32_t)f2bf(sl[2 * lane + 1]) << 16) | (uint32_t)f2bf(sl[2 * lane]);
    } else if (wv == 1 || wv == 6) {
      int gb = (wv == 1) ? 0 : 5;
      float p5[5];
      float s0 = sl[lane], s1 = sl[lane + 64];
#pragma unroll
      for (int g = 0; g < 5; ++g)
        p5[g] = s0 * W1[(gb + g) * 256 + lane] + s1 * W1[(gb + g) * 256 + 64 + lane];
#pragma unroll
      for (int off = 1; off < 64; off <<= 1) {
#pragma unroll
        for (int g = 0; g < 5; ++g) p5[g] += __shfl_xor(p5[g], off);
      }
      if (lane < 5) qv[gb + lane] = p5[lane];
    } else if (wv < 6) {   // waves 2-5: logits, 3-level kg-reduce, direct store
      int v = ((wv - 2) << 3) + (lane >> 3), kg = lane & 7;
      const float* w3p = W3 + v * 128 + kg * 16;
      const float* slp = sl + kg * 16;
      float a = 0.f;
#pragma unroll
      for (int k = 0; k < 16; ++k) a += slp[k] * w3p[k];
      a += __shfl_xor(a, 1);
      a += __shfl_xor(a, 2);
      a += __shfl_xor(a, 4);
      if (kg == 0) Lg[(size_t)ty * (B_ * VOUT_) + b * VOUT_ + v] = a + b3[v];
    }
    __syncthreads();
    // no end-of-loop barrier: red is re-written only after the e-phase barrier;
    // qv/xpk writes above are barrier-separated from their readers.
  }
}

// ---------------- batch-softmax: per (ty,v) max & sum over b
__global__ __launch_bounds__(256) void k_red(const float* __restrict__ Lg, float2* __restrict__ MS) {
  int ty = blockIdx.x >> 5, v = blockIdx.x & 31;
  const float* src = Lg + (size_t)ty * (B_ * VOUT_) + v;
  int tid = threadIdx.x, lane = tid & 63, wv = tid >> 6;
  __shared__ float r8[8];
  float m = -3.4e38f;
  for (int bb = tid; bb < B_; bb += 256) m = fmaxf(m, src[(size_t)bb * VOUT_]);
#pragma unroll
  for (int off = 1; off < 64; off <<= 1) m = fmaxf(m, __shfl_xor(m, off));
  if (lane == 0) r8[wv] = m;
  __syncthreads();
  float mx = fmaxf(fmaxf(r8[0], r8[1]), fmaxf(r8[2], r8[3]));
  float s = 0.f;
  for (int bb = tid; bb < B_; bb += 256) s += __expf(src[(size_t)bb * VOUT_] - mx);
#pragma unroll
  for (int off = 1; off < 64; off <<= 1) s += __shfl_xor(s, off);
  __syncthreads();
  if (lane == 0) r8[4 + wv] = s;
  __syncthreads();
  if (tid == 0) MS[blockIdx.x] = make_float2(mx, r8[4] + r8[5] + r8[6] + r8[7]);
}

__global__ __launch_bounds__(256) void k_out(const float* __restrict__ Lg,
                                             const float2* __restrict__ MS,
                                             float* __restrict__ out) {
  int i = blockIdx.x * 256 + threadIdx.x;          // < 1048576, layout (ty,b,v)
  int ty = i >> 15, b = (i >> 5) & 1023, v = i & 31;
  float2 ms = MS[ty * 32 + v];
  out[(size_t)b * (TY_ * VOUT_) + ty * VOUT_ + v] = __expf(Lg[i] - ms.x) / ms.y;
}

// ---------------- ws layout (bytes): pre16 134217728 | Wsw 262144 | Lg 4194304 | MS 8192
#define WS_PRE 0
#define WS_WSW 134217728
#define WS_LG  134479872
#define WS_MS  138674176

extern "C" void kernel_launch(void* const* d_in, const int* in_sizes, int n_in,
                              void* d_out, int out_size, void* d_ws, size_t ws_size,
                              hipStream_t stream) {
  const float* X     = (const float*)d_in[0];
  const float* Wih_f = (const float*)d_in[1];
  const float* Whh_f = (const float*)d_in[2];
  const float* bih_f = (const float*)d_in[3];
  const float* bhh_f = (const float*)d_in[4];
  const float* Wih_b = (const float*)d_in[5];
  const float* Whh_b = (const float*)d_in[6];
  const float* bih_b = (const float*)d_in[7];
  const float* bhh_b = (const float*)d_in[8];
  const float* Wih_p = (const float*)d_in[9];
  const float* Whh_p = (const float*)d_in[10];
  const float* bih_p = (const float*)d_in[11];
  const float* bhh_p = (const float*)d_in[12];
  const float* W1    = (const float*)d_in[13];
  const float* b1    = (const float*)d_in[14];
  const float* W2    = (const float*)d_in[15];
  const float* b2    = (const float*)d_in[16];
  const float* W3    = (const float*)d_in[17];
  const float* b3    = (const float*)d_in[18];

  char* ws = (char*)d_ws;
  unsigned short* pre16 = (unsigned short*)(ws + WS_PRE);
  unsigned short* Wsw   = (unsigned short*)(ws + WS_WSW);
  float*          Lg    = (float*)(ws + WS_LG);
  float2*         MS    = (float2*)(ws + WS_MS);

  // opt into >64KB dynamic LDS for k_dec (idempotent; host-side, capture-safe)
  (void)hipFuncSetAttribute((const void*)k_dec, hipFuncAttributeMaxDynamicSharedMemorySize, DSM_);

  k_prep<<<512, 256, 0, stream>>>(Wih_p, Whh_p, Wsw);
  k_enc<<<64, 512, 0, stream>>>(X, Wih_f, Whh_f, bih_f, bhh_f,
                                Wih_b, Whh_b, bih_b, bhh_b, pre16);
  k_dec<<<1024, 512, DSM_, stream>>>(pre16, Wsw, W1, b1, W2, b2, W3, b3,
                                     bih_p, bhh_p, Lg);
  k_red<<<1024, 256, 0, stream>>>(Lg, MS);
  k_out<<<4096, 256, 0, stream>>>(Lg, MS, (float*)d_out);
}

// Round 12
// 1388.995 us; speedup vs baseline: 1.2823x; 1.2823x over previous
//
#include <hip/hip_runtime.h>
#include <stdint.h>

#define B_    1024
#define TX_   512
#define TY_   32
#define NA_   64
#define NS_   128
#define VIN_  64
#define VOUT_ 32

typedef short v8s __attribute__((ext_vector_type(8)));   // 8 bf16 (4 VGPRs)
typedef float v4f __attribute__((ext_vector_type(4)));   // 4 fp32 acc
typedef uint32_t v4u __attribute__((ext_vector_type(4)));

__device__ __forceinline__ unsigned short f2bf(float f) {
  union { float f; uint32_t u; } v; v.f = f;
  return (unsigned short)((v.u + 0x7fffu + ((v.u >> 16) & 1u)) >> 16);  // RNE
}
__device__ __forceinline__ float bflo(uint32_t p) { union { uint32_t u; float f; } v; v.u = p << 16; return v.f; }
__device__ __forceinline__ float bfhi(uint32_t p) { union { uint32_t u; float f; } v; v.u = p & 0xffff0000u; return v.f; }
__device__ __forceinline__ float sigm(float x)   { return 1.0f / (1.0f + __expf(-x)); }
__device__ __forceinline__ float tanh_f(float x) { return 1.0f - 2.0f / (__expf(2.0f * x) + 1.0f); }
// HW packed f32->bf16 (RNE, same as f2bf): 1 instr for 2 elements [learn_hip m214v22]
__device__ __forceinline__ uint32_t pkbf(float lo, float hi) {
  uint32_t r;
  asm("v_cvt_pk_bf16_f32 %0, %1, %2" : "=v"(r) : "v"(lo), "v"(hi));
  return r;
}

// ---------------- prep: Wcat = [Wih_p | Whh_p] -> bf16 in MFMA B-frag order.
// frag f covers rows [(f>>3)*16, +16) x cols [(f&7)*32, +32).
// lane (n = lane&15, q = lane>>4) element j holds Wcat[(f>>3)*16 + n][(f&7)*32 + q*8 + j].
// linear short index = f*512 + lane*8 + j  -> 16B/lane coalesced v8s loads in k_dec.
// k_dec (512 thr): frag f = (wv*4+nt)*8+kt -> rows 64wv+16nt, cols kt*32.
__global__ __launch_bounds__(256) void k_prep(const float* __restrict__ Wih_p,
                                              const float* __restrict__ Whh_p,
                                              unsigned short* __restrict__ Wsw) {
  int i = blockIdx.x * 256 + threadIdx.x;   // < 131072
  int j = i & 7, lane = (i >> 3) & 63, f = i >> 9;
  int r = (f >> 3) * 16 + (lane & 15);
  int c = (f & 7) * 32 + (lane >> 4) * 8 + j;
  float w = (c < 128) ? Wih_p[r * 128 + c] : Whh_p[r * 128 + (c - 128)];
  Wsw[i] = f2bf(w);
}

// ---------------- encoder: 128 blocks = (64 batch-groups x 2 dirs), 256 thr (R10 config —
// R11 proved k_enc is VALU-throughput-bound per CU: merging dirs halved active CUs, 1.6x
// slower. 128 blocks = 128 CUs is the max spread: hidden can't split (recurrence needs
// full h), batch can't go below MFMA M=16.)
// R12: (a) double-buffered hl (verified R11) -> 1 barrier/step; (b) x-conversion via
// v_cvt_pk_bf16_f32 (8 instrs vs ~70 manual f2bf+insert ops -> ~40% VALU cut).
__global__ __launch_bounds__(256) void k_enc(
    const float* __restrict__ X,
    const float* __restrict__ Wih_f, const float* __restrict__ Whh_f,
    const float* __restrict__ bih_f, const float* __restrict__ bhh_f,
    const float* __restrict__ Wih_b, const float* __restrict__ Whh_b,
    const float* __restrict__ bih_b, const float* __restrict__ bhh_b,
    unsigned short* __restrict__ pre16)
{
  const int tid = threadIdx.x, lane = tid & 63, wv = tid >> 6;
  const int dir = blockIdx.x & 1, b0 = (blockIdx.x >> 1) * 16;
  const int n = lane & 15, q = lane >> 4, hs = wv * 16;
  const float* Wih = dir ? Wih_b : Wih_f;
  const float* Whh = dir ? Whh_b : Whh_f;
  const float* bih = dir ? bih_b : bih_f;
  const float* bhh = dir ? bhh_b : bhh_f;

  __shared__ __align__(16) unsigned short hl[2][16 * 72];  // dbuf, 144B rows

  v8s wx[4][2], wh[4][2];
  float bias[4];
#pragma unroll
  for (int g = 0; g < 4; ++g) {
    int row = g * 64 + hs + n;
    bias[g] = bih[row] + bhh[row];
#pragma unroll
    for (int kt = 0; kt < 2; ++kt) {
      const float* pi = Wih + row * 64 + kt * 32 + q * 8;
      const float* ph = Whh + row * 64 + kt * 32 + q * 8;
      v8s a, bb;
#pragma unroll
      for (int j = 0; j < 8; ++j) { a[j] = (short)f2bf(pi[j]); bb[j] = (short)f2bf(ph[j]); }
      wx[g][kt] = a; wh[g][kt] = bb;
    }
  }
  for (int i = tid; i < 2 * 16 * 36; i += 256) ((uint32_t*)hl)[i] = 0u;

  float c[4] = {0.f, 0.f, 0.f, 0.f};
  const float* xrow = X + (size_t)(b0 + n) * (TX_ * VIN_) + q * 8;  // A-frag m = lane&15
  int t0 = dir ? (TX_ - 1) : 0;
  float4 pf0 = *(const float4*)(xrow + t0 * VIN_ + 0);
  float4 pf1 = *(const float4*)(xrow + t0 * VIN_ + 4);
  float4 pf2 = *(const float4*)(xrow + t0 * VIN_ + 32);
  float4 pf3 = *(const float4*)(xrow + t0 * VIN_ + 36);
  __syncthreads();

  for (int t = 0; t < TX_; ++t) {
    union { v4u u; v8s s; } c0, c1;
    c0.u[0] = pkbf(pf0.x, pf0.y); c0.u[1] = pkbf(pf0.z, pf0.w);
    c0.u[2] = pkbf(pf1.x, pf1.y); c0.u[3] = pkbf(pf1.z, pf1.w);
    c1.u[0] = pkbf(pf2.x, pf2.y); c1.u[1] = pkbf(pf2.z, pf2.w);
    c1.u[2] = pkbf(pf3.x, pf3.y); c1.u[3] = pkbf(pf3.z, pf3.w);
    v8s xa0 = c0.s, xa1 = c1.s;
    int tn = (t + 1 < TX_) ? t + 1 : t;
    int ti = dir ? (TX_ - 1 - tn) : tn;
    pf0 = *(const float4*)(xrow + ti * VIN_ + 0);
    pf1 = *(const float4*)(xrow + ti * VIN_ + 4);
    pf2 = *(const float4*)(xrow + ti * VIN_ + 32);
    pf3 = *(const float4*)(xrow + ti * VIN_ + 36);

    const char* hb_ = (const char*)hl[t & 1];
    v8s ha0 = *(const v8s*)(hb_ + (lane & 15) * 144 + q * 16);
    v8s ha1 = *(const v8s*)(hb_ + (lane & 15) * 144 + 64 + q * 16);
    v4f acc[4];
#pragma unroll
    for (int g = 0; g < 4; ++g) {
      v4f a = {bias[g], bias[g], bias[g], bias[g]};
      a = __builtin_amdgcn_mfma_f32_16x16x32_bf16(xa0, wx[g][0], a, 0, 0, 0);
      a = __builtin_amdgcn_mfma_f32_16x16x32_bf16(xa1, wx[g][1], a, 0, 0, 0);
      a = __builtin_amdgcn_mfma_f32_16x16x32_bf16(ha0, wh[g][0], a, 0, 0, 0);
      a = __builtin_amdgcn_mfma_f32_16x16x32_bf16(ha1, wh[g][1], a, 0, 0, 0);
      acc[g] = a;
    }
    int t_out = dir ? (TX_ - 1 - t) : t;
    char* hw_ = (char*)hl[(t & 1) ^ 1];
#pragma unroll
    for (int r = 0; r < 4; ++r) {   // C/D: col=lane&15 (hidden), row=q*4+r (batch)
      float cc = sigm(acc[1][r]) * c[r] + sigm(acc[0][r]) * tanh_f(acc[2][r]);
      c[r] = cc;
      float h = sigm(acc[3][r]) * tanh_f(cc);
      int m = q * 4 + r;
      unsigned short hb = f2bf(h);
      *((unsigned short*)(hw_ + m * 144) + hs + n) = hb;
      pre16[((size_t)(b0 + m) * TX_ + t_out) * NS_ + dir * 64 + hs + n] = hb;
    }
    __syncthreads();   // write(t)->read(t+1) on hl[t^1]; read(t)->write(t+1) on hl[t]
  }
}

// ---------------- decoder: 1 block per batch element, 512 threads (8 waves, 2 waves/SIMD).
// Locked-in: VGPR cap = 65536/block (R1-R5); po LDS-resident (R8); 1 block/CU.
// Structure: R9 weight-stream + R10 6-barrier step (best measured: 718us). UNCHANGED.
#define PO_   0
#define PP_   139264
#define EA_   149504
#define RED_  151552
#define ZB_   155648
#define SL_   157696
#define XPK_  158208
#define QV_   159232
#define RR_   159296
#define DSM_  159360

__global__ __launch_bounds__(512) void k_dec(
    const unsigned short* __restrict__ pre16,
    const unsigned short* __restrict__ Wsw,
    const float* __restrict__ W1, const float* __restrict__ b1,
    const float* __restrict__ W2, const float* __restrict__ b2,
    const float* __restrict__ W3, const float* __restrict__ b3,
    const float* __restrict__ bih_p, const float* __restrict__ bhh_p,
    float* __restrict__ Lg)
{
  extern __shared__ char smem[];
  char* po = smem + PO_;
  unsigned short* P = (unsigned short*)(smem + PP_);
  float* ea  = (float*)(smem + EA_);
  float* red = (float*)(smem + RED_);
  float* zbf = (float*)(smem + ZB_);
  float* sl  = (float*)(smem + SL_);
  uint32_t* xpk = (uint32_t*)(smem + XPK_);
  float* qv  = (float*)(smem + QV_);
  float* rr  = (float*)(smem + RR_);

  const int b = blockIdx.x, tid = threadIdx.x, lane = tid & 63, wv = tid >> 6;

  { // stage pre_out[b] -> padded LDS rows (272B stride, b128-aligned)
    const uint4* src = (const uint4*)((const char*)pre16 + (size_t)b * (TX_ * NS_ * 2));
    for (int i = tid; i < TX_ * 16; i += 512) {
      int t = i >> 4, d8 = i & 15;
      *(uint4*)(po + t * 272 + d8 * 16) = src[i];
    }
  }
  if (tid < 128) { sl[tid] = 0.f; xpk[tid] = 0u; }
  if (tid < 16) qv[tid] = 0.f;               // q for step 0: s0 = 0 -> q = 0
  float* w1p = (float*)(smem + RED_);   // 1280-float staging (RED_+ZB_ space, prologue only)
  for (int i = tid; i < 1280; i += 512) { int g = i >> 7, k = i & 127; w1p[i] = W1[g * 256 + 128 + k]; }
  __syncthreads();
  { // P[t][g] = pre_out[t] @ W1[:,128:].T + b1   (thread = t)
    int t = tid;
    float a[10];
#pragma unroll
    for (int g = 0; g < 10; ++g) a[g] = b1[g];
    for (int k2 = 0; k2 < 64; ++k2) {
      uint32_t pr = *(const uint32_t*)(po + t * 272 + k2 * 4);
      float lo = bflo(pr), hi = bfhi(pr);
#pragma unroll
      for (int g = 0; g < 10; ++g) a[g] += lo * w1p[g * 128 + 2 * k2] + hi * w1p[g * 128 + 2 * k2 + 1];
    }
#pragma unroll
    for (int g = 0; g < 10; ++g) P[t * 10 + g] = f2bf(a[g]);
  }

  // per-wave weight stream base: frag j = nt*8+kt at wp[j*64]; wave wv owns z rows [64wv, 64wv+64)
  const v8s* wp = (const v8s*)Wsw + (size_t)(wv * 32) * 64 + lane;
  float bp4[4];
#pragma unroll
  for (int nt = 0; nt < 4; ++nt) {
    int r = wv * 64 + nt * 16 + (lane & 15);
    bp4[nt] = bih_p[r] + bhh_p[r];
  }
  float creg = 0.f;
  __syncthreads();

  for (int ty = 0; ty < TY_; ++ty) {
    // ---- step-top weight issue: nt0+nt1 (16 frags, 64 VGPRs); covered by e-phase+context.
    v8s wA[4], wB[4], wC[4], wD[4], wE[4];
#pragma unroll
    for (int k = 0; k < 4; ++k) wA[k] = wp[k * 64];
#pragma unroll
    for (int k = 0; k < 4; ++k) wB[k] = wp[(4 + k) * 64];
#pragma unroll
    for (int k = 0; k < 4; ++k) wC[k] = wp[(8 + k) * 64];
#pragma unroll
    for (int k = 0; k < 4; ++k) wD[k] = wp[(12 + k) * 64];

    // ---- e_t (thread = t); no max-subtraction (e = relu(.) bounded ~1, exp <= ~3).
    // Single barrier: ea[t] = p UNNORMALIZED; /S deferred to the fold phase.
    {
      float qr[10];
#pragma unroll
      for (int g = 0; g < 10; ++g) qr[g] = qv[g];
      const uint32_t* Pt = (const uint32_t*)(const void*)P + tid * 5;
      float acc = b2[0];
#pragma unroll
      for (int i = 0; i < 5; ++i) {
        uint32_t pr = Pt[i];
        acc += W2[2 * i]     * tanh_f(bflo(pr) + qr[2 * i]);
        acc += W2[2 * i + 1] * tanh_f(bfhi(pr) + qr[2 * i + 1]);
      }
      float e = fmaxf(acc, 0.f);
      float p = __expf(e);
      ea[tid] = p;
      float s = p;
#pragma unroll
      for (int off = 1; off < 64; off <<= 1) s += __shfl_xor(s, off);
      if (lane == 0) rr[wv] = s;
    }
    __syncthreads();
    // ---- context partials = sum_t p_t * pre_out[t]  (lane=(d8,g4), t = i*32 + wv*4 + g4)
    {
      int d8 = lane & 15, g4 = lane >> 4, tg = wv * 4 + g4;
      float p8[8];
#pragma unroll
      for (int j = 0; j < 8; ++j) p8[j] = 0.f;
      for (int i = 0; i < 16; ++i) {
        int t = i * 32 + tg;
        float al = ea[t];
        uint4 pk = *(const uint4*)(po + t * 272 + d8 * 16);
        p8[0] += al * bflo(pk.x); p8[1] += al * bfhi(pk.x);
        p8[2] += al * bflo(pk.y); p8[3] += al * bfhi(pk.y);
        p8[4] += al * bflo(pk.z); p8[5] += al * bfhi(pk.z);
        p8[6] += al * bflo(pk.w); p8[7] += al * bfhi(pk.w);
      }
#pragma unroll
      for (int off = 16; off < 64; off <<= 1) {
#pragma unroll
        for (int j = 0; j < 8; ++j) p8[j] += __shfl_xor(p8[j], off);
      }
      if (lane < 16) {
        float4* dst = (float4*)&red[wv * 128 + d8 * 8];
        dst[0] = make_float4(p8[0], p8[1], p8[2], p8[3]);
        dst[1] = make_float4(p8[4], p8[5], p8[6], p8[7]);
      }
    }
    // ---- post-context weight issue: nt2-lo (wE). p8 dead here; live bufs = 5 (80 VGPR).
#pragma unroll
    for (int k = 0; k < 4; ++k) wE[k] = wp[(16 + k) * 64];
    __syncthreads();
    // ---- fold 8 wave-partials, normalize by S (from rr), pack ctx -> xpk[0..63]
    if (tid < 64) {
      float s8 = rr[tid & 7];
#pragma unroll
      for (int off = 1; off < 8; off <<= 1) s8 += __shfl_xor(s8, off);
      float rS = 1.0f / s8;
      float v0 = 0.f, v1 = 0.f;
#pragma unroll
      for (int w = 0; w < 8; ++w) { v0 += red[w * 128 + 2 * tid]; v1 += red[w * 128 + 2 * tid + 1]; }
      xpk[tid] = ((uint32_t)f2bf(v1 * rS) << 16) | (uint32_t)f2bf(v0 * rS);
    }
    __syncthreads();
    // ---- z = Wcat @ [ctx; s] + bp via MFMA. Broadcast-A: all 16 A-rows hold x (row 0 of
    // D is unaffected), so every lane loads xpk directly (LDS broadcast) - no cndmask.
    // Dual-acc interleave breaks the 8-deep dependent MFMA chains. Refills reuse dead bufs.
    {
      const char* xb = (const char*)xpk + (lane >> 4) * 16;
      v4f a0 = {0.f, 0.f, 0.f, 0.f}, a1 = {0.f, 0.f, 0.f, 0.f};
      v8s x0, x1;
      x0 = *(const v8s*)(xb + 0 * 64);
      x1 = *(const v8s*)(xb + 1 * 64);
      a0 = __builtin_amdgcn_mfma_f32_16x16x32_bf16(x0, wA[0], a0, 0, 0, 0);
      a1 = __builtin_amdgcn_mfma_f32_16x16x32_bf16(x0, wC[0], a1, 0, 0, 0);
      a0 = __builtin_amdgcn_mfma_f32_16x16x32_bf16(x1, wA[1], a0, 0, 0, 0);
      a1 = __builtin_amdgcn_mfma_f32_16x16x32_bf16(x1, wC[1], a1, 0, 0, 0);
      x0 = *(const v8s*)(xb + 2 * 64);
      x1 = *(const v8s*)(xb + 3 * 64);
      a0 = __builtin_amdgcn_mfma_f32_16x16x32_bf16(x0, wA[2], a0, 0, 0, 0);
      a1 = __builtin_amdgcn_mfma_f32_16x16x32_bf16(x0, wC[2], a1, 0, 0, 0);
      a0 = __builtin_amdgcn_mfma_f32_16x16x32_bf16(x1, wA[3], a0, 0, 0, 0);
      a1 = __builtin_amdgcn_mfma_f32_16x16x32_bf16(x1, wC[3], a1, 0, 0, 0);
      // wA,wC consumed -> stream nt2-hi into wA, nt3-lo into wC
#pragma unroll
      for (int k = 0; k < 4; ++k) wA[k] = wp[(20 + k) * 64];
#pragma unroll
      for (int k = 0; k < 4; ++k) wC[k] = wp[(24 + k) * 64];
      x0 = *(const v8s*)(xb + 4 * 64);
      x1 = *(const v8s*)(xb + 5 * 64);
      a0 = __builtin_amdgcn_mfma_f32_16x16x32_bf16(x0, wB[0], a0, 0, 0, 0);
      a1 = __builtin_amdgcn_mfma_f32_16x16x32_bf16(x0, wD[0], a1, 0, 0, 0);
      a0 = __builtin_amdgcn_mfma_f32_16x16x32_bf16(x1, wB[1], a0, 0, 0, 0);
      a1 = __builtin_amdgcn_mfma_f32_16x16x32_bf16(x1, wD[1], a1, 0, 0, 0);
      x0 = *(const v8s*)(xb + 6 * 64);
      x1 = *(const v8s*)(xb + 7 * 64);
      a0 = __builtin_amdgcn_mfma_f32_16x16x32_bf16(x0, wB[2], a0, 0, 0, 0);
      a1 = __builtin_amdgcn_mfma_f32_16x16x32_bf16(x0, wD[2], a1, 0, 0, 0);
      a0 = __builtin_amdgcn_mfma_f32_16x16x32_bf16(x1, wB[3], a0, 0, 0, 0);
      a1 = __builtin_amdgcn_mfma_f32_16x16x32_bf16(x1, wD[3], a1, 0, 0, 0);
      // wB,wD consumed -> stream nt3-hi into wB
#pragma unroll
      for (int k = 0; k < 4; ++k) wB[k] = wp[(28 + k) * 64];
      if (lane < 16) {
        zbf[wv * 64 + lane]      = a0[0] + bp4[0];   // D[0][n] on lanes 0..15, reg 0
        zbf[wv * 64 + 16 + lane] = a1[0] + bp4[1];
      }
      v4f a2 = {0.f, 0.f, 0.f, 0.f}, a3 = {0.f, 0.f, 0.f, 0.f};
      x0 = *(const v8s*)(xb + 0 * 64);
      x1 = *(const v8s*)(xb + 1 * 64);
      a2 = __builtin_amdgcn_mfma_f32_16x16x32_bf16(x0, wE[0], a2, 0, 0, 0);
      a3 = __builtin_amdgcn_mfma_f32_16x16x32_bf16(x0, wC[0], a3, 0, 0, 0);
      a2 = __builtin_amdgcn_mfma_f32_16x16x32_bf16(x1, wE[1], a2, 0, 0, 0);
      a3 = __builtin_amdgcn_mfma_f32_16x16x32_bf16(x1, wC[1], a3, 0, 0, 0);
      x0 = *(const v8s*)(xb + 2 * 64);
      x1 = *(const v8s*)(xb + 3 * 64);
      a2 = __builtin_amdgcn_mfma_f32_16x16x32_bf16(x0, wE[2], a2, 0, 0, 0);
      a3 = __builtin_amdgcn_mfma_f32_16x16x32_bf16(x0, wC[2], a3, 0, 0, 0);
      a2 = __builtin_amdgcn_mfma_f32_16x16x32_bf16(x1, wE[3], a2, 0, 0, 0);
      a3 = __builtin_amdgcn_mfma_f32_16x16x32_bf16(x1, wC[3], a3, 0, 0, 0);
      x0 = *(const v8s*)(xb + 4 * 64);
      x1 = *(const v8s*)(xb + 5 * 64);
      a2 = __builtin_amdgcn_mfma_f32_16x16x32_bf16(x0, wA[0], a2, 0, 0, 0);
      a3 = __builtin_amdgcn_mfma_f32_16x16x32_bf16(x0, wB[0], a3, 0, 0, 0);
      a2 = __builtin_amdgcn_mfma_f32_16x16x32_bf16(x1, wA[1], a2, 0, 0, 0);
      a3 = __builtin_amdgcn_mfma_f32_16x16x32_bf16(x1, wB[1], a3, 0, 0, 0);
      x0 = *(const v8s*)(xb + 6 * 64);
      x1 = *(const v8s*)(xb + 7 * 64);
      a2 = __builtin_amdgcn_mfma_f32_16x16x32_bf16(x0, wA[2], a2, 0, 0, 0);
      a3 = __builtin_amdgcn_mfma_f32_16x16x32_bf16(x0, wB[2], a3, 0, 0, 0);
      a2 = __builtin_amdgcn_mfma_f32_16x16x32_bf16(x1, wA[3], a2, 0, 0, 0);
      a3 = __builtin_amdgcn_mfma_f32_16x16x32_bf16(x1, wB[3], a3, 0, 0, 0);
      if (lane < 16) {
        zbf[wv * 64 + 32 + lane] = a2[0] + bp4[2];
        zbf[wv * 64 + 48 + lane] = a3[0] + bp4[3];
      }
    }
    __syncthreads();
    if (tid < 128) {   // gate merge, torch order i,f,g,o
      float zi = zbf[tid], zf = zbf[128 + tid], zg = zbf[256 + tid], zo = zbf[384 + tid];
      creg = sigm(zf) * creg + sigm(zi) * tanh_f(zg);
      sl[tid] = sigm(zo) * tanh_f(creg);
    }
    __syncthreads();
    // ---- merged phase: wave0 packs s; waves 1&6 split next-step q (5 gates each);
    //      waves 2-5 in-wave logits with DIRECT Lg store (v=(wv-2)*8+(lane>>3), kg=lane&7)
    if (wv == 0) {
      xpk[64 + lane] = ((uint32_t)f2bf(sl[2 * lane + 1]) << 16) | (uint32_t)f2bf(sl[2 * lane]);
    } else if (wv == 1 || wv == 6) {
      int gb = (wv == 1) ? 0 : 5;
      float p5[5];
      float s0 = sl[lane], s1 = sl[lane + 64];
#pragma unroll
      for (int g = 0; g < 5; ++g)
        p5[g] = s0 * W1[(gb + g) * 256 + lane] + s1 * W1[(gb + g) * 256 + 64 + lane];
#pragma unroll
      for (int off = 1; off < 64; off <<= 1) {
#pragma unroll
        for (int g = 0; g < 5; ++g) p5[g] += __shfl_xor(p5[g], off);
      }
      if (lane < 5) qv[gb + lane] = p5[lane];
    } else if (wv < 6) {   // waves 2-5: logits, 3-level kg-reduce, direct store
      int v = ((wv - 2) << 3) + (lane >> 3), kg = lane & 7;
      const float* w3p = W3 + v * 128 + kg * 16;
      const float* slp = sl + kg * 16;
      float a = 0.f;
#pragma unroll
      for (int k = 0; k < 16; ++k) a += slp[k] * w3p[k];
      a += __shfl_xor(a, 1);
      a += __shfl_xor(a, 2);
      a += __shfl_xor(a, 4);
      if (kg == 0) Lg[(size_t)ty * (B_ * VOUT_) + b * VOUT_ + v] = a + b3[v];
    }
    __syncthreads();
    // no end-of-loop barrier: red is re-written only after the e-phase barrier;
    // qv/xpk writes above are barrier-separated from their readers.
  }
}

// ---------------- batch-softmax: per (ty,v) max & sum over b
__global__ __launch_bounds__(256) void k_red(const float* __restrict__ Lg, float2* __restrict__ MS) {
  int ty = blockIdx.x >> 5, v = blockIdx.x & 31;
  const float* src = Lg + (size_t)ty * (B_ * VOUT_) + v;
  int tid = threadIdx.x, lane = tid & 63, wv = tid >> 6;
  __shared__ float r8[8];
  float m = -3.4e38f;
  for (int bb = tid; bb < B_; bb += 256) m = fmaxf(m, src[(size_t)bb * VOUT_]);
#pragma unroll
  for (int off = 1; off < 64; off <<= 1) m = fmaxf(m, __shfl_xor(m, off));
  if (lane == 0) r8[wv] = m;
  __syncthreads();
  float mx = fmaxf(fmaxf(r8[0], r8[1]), fmaxf(r8[2], r8[3]));
  float s = 0.f;
  for (int bb = tid; bb < B_; bb += 256) s += __expf(src[(size_t)bb * VOUT_] - mx);
#pragma unroll
  for (int off = 1; off < 64; off <<= 1) s += __shfl_xor(s, off);
  __syncthreads();
  if (lane == 0) r8[4 + wv] = s;
  __syncthreads();
  if (tid == 0) MS[blockIdx.x] = make_float2(mx, r8[4] + r8[5] + r8[6] + r8[7]);
}

__global__ __launch_bounds__(256) void k_out(const float* __restrict__ Lg,
                                             const float2* __restrict__ MS,
                                             float* __restrict__ out) {
  int i = blockIdx.x * 256 + threadIdx.x;          // < 1048576, layout (ty,b,v)
  int ty = i >> 15, b = (i >> 5) & 1023, v = i & 31;
  float2 ms = MS[ty * 32 + v];
  out[(size_t)b * (TY_ * VOUT_) + ty * VOUT_ + v] = __expf(Lg[i] - ms.x) / ms.y;
}

// ---------------- ws layout (bytes): pre16 134217728 | Wsw 262144 | Lg 4194304 | MS 8192
#define WS_PRE 0
#define WS_WSW 134217728
#define WS_LG  134479872
#define WS_MS  138674176

extern "C" void kernel_launch(void* const* d_in, const int* in_sizes, int n_in,
                              void* d_out, int out_size, void* d_ws, size_t ws_size,
                              hipStream_t stream) {
  const float* X     = (const float*)d_in[0];
  const float* Wih_f = (const float*)d_in[1];
  const float* Whh_f = (const float*)d_in[2];
  const float* bih_f = (const float*)d_in[3];
  const float* bhh_f = (const float*)d_in[4];
  const float* Wih_b = (const float*)d_in[5];
  const float* Whh_b = (const float*)d_in[6];
  const float* bih_b = (const float*)d_in[7];
  const float* bhh_b = (const float*)d_in[8];
  const float* Wih_p = (const float*)d_in[9];
  const float* Whh_p = (const float*)d_in[10];
  const float* bih_p = (const float*)d_in[11];
  const float* bhh_p = (const float*)d_in[12];
  const float* W1    = (const float*)d_in[13];
  const float* b1    = (const float*)d_in[14];
  const float* W2    = (const float*)d_in[15];
  const float* b2    = (const float*)d_in[16];
  const float* W3    = (const float*)d_in[17];
  const float* b3    = (const float*)d_in[18];

  char* ws = (char*)d_ws;
  unsigned short* pre16 = (unsigned short*)(ws + WS_PRE);
  unsigned short* Wsw   = (unsigned short*)(ws + WS_WSW);
  float*          Lg    = (float*)(ws + WS_LG);
  float2*         MS    = (float2*)(ws + WS_MS);

  // opt into >64KB dynamic LDS for k_dec (idempotent; host-side, capture-safe)
  (void)hipFuncSetAttribute((const void*)k_dec, hipFuncAttributeMaxDynamicSharedMemorySize, DSM_);

  k_prep<<<512, 256, 0, stream>>>(Wih_p, Whh_p, Wsw);
  k_enc<<<128, 256, 0, stream>>>(X, Wih_f, Whh_f, bih_f, bhh_f,
                                 Wih_b, Whh_b, bih_b, bhh_b, pre16);
  k_dec<<<1024, 512, DSM_, stream>>>(pre16, Wsw, W1, b1, W2, b2, W3, b3,
                                     bih_p, bhh_p, Lg);
  k_red<<<1024, 256, 0, stream>>>(Lg, MS);
  k_out<<<4096, 256, 0, stream>>>(Lg, MS, (float*)d_out);
}